// Round 5
// baseline (422.110 us; speedup 1.0000x reference)
//
#include <hip/hip_runtime.h>
#include <hip/hip_fp16.h>
#include <cstdint>
#include <cstddef>

#define INF_  128
#define OUTF  64
#define ALPHA 0.2f
#define LN_EPS 1e-5f

#define NB    1024        // coarse buckets (src >> 7)
#define LOCB  7           // 128 local nodes per bucket
#define NBLK  512         // edge-partition blocks for count/scatter passes
#define LDSE  6144        // per-bucket LDS edge capacity (mean 4096, +32 sigma)

// ---------------- GEMM: h(fp16) = x @ W^T + b, sl = h@a_l, sr = h@a_r ----------------
__global__ __launch_bounds__(256) void gemm_kernel(
    const float* __restrict__ x, const float* __restrict__ W,
    const float* __restrict__ b, const float* __restrict__ a,
    __half* __restrict__ hh, float* __restrict__ sl, float* __restrict__ sr, int n)
{
    __shared__ float4 Wq[32][64];          // Wq[kq][o]: lane-stride 16B, conflict-free
    __shared__ float4 xs[4][8][32];

    const int tid  = threadIdx.x;
    const int lane = tid & 63;
    const int wv   = tid >> 6;

    for (int idx = tid; idx < 2048; idx += 256) {
        int kq = idx >> 6, o = idx & 63;
        Wq[kq][o] = ((const float4*)W)[o * 32 + kq];
    }
    __syncthreads();

    const float bb = b[lane];
    const float al = a[lane];
    const float ar = a[OUTF + lane];

    const int ngroups = (n + 31) >> 5;
    for (int g = blockIdx.x; g < ngroups; g += gridDim.x) {
        const int node0 = g * 32 + wv * 8;
        for (int t = lane; t < 8 * 32; t += 64) {
            int r = t >> 5, q = t & 31;
            int nd = node0 + r; if (nd >= n) nd = 0;
            xs[wv][r][q] = ((const float4*)x)[(size_t)nd * 32 + q];
        }
        __syncthreads();

        float acc[8];
        #pragma unroll
        for (int r = 0; r < 8; r++) acc[r] = bb;

        #pragma unroll 4
        for (int kq = 0; kq < 32; kq++) {
            const float4 wq = Wq[kq][lane];
            #pragma unroll
            for (int r = 0; r < 8; r++) {
                const float4 xq = xs[wv][r][kq];   // wave-uniform broadcast read
                acc[r] = fmaf(wq.x, xq.x, acc[r]);
                acc[r] = fmaf(wq.y, xq.y, acc[r]);
                acc[r] = fmaf(wq.z, xq.z, acc[r]);
                acc[r] = fmaf(wq.w, xq.w, acc[r]);
            }
        }

        #pragma unroll
        for (int r = 0; r < 8; r++) {
            const int node = node0 + r;
            const float v = acc[r];
            float p = v * al, q = v * ar;
            for (int s = 32; s; s >>= 1) {
                p += __shfl_down(p, s);
                q += __shfl_down(q, s);
            }
            if (node < n) {
                hh[(size_t)node * OUTF + lane] = __float2half(v);
                if (lane == 0) { sl[node] = p; sr[node] = q; }
            }
        }
        __syncthreads();
    }
}

// ---------------- coarse radix by src>>7 (LDS atomics only) ----------------
__global__ __launch_bounds__(256) void count_coarse(
    const int* __restrict__ src, int* __restrict__ M, int E)
{
    __shared__ int hist[NB];
    for (int i = threadIdx.x; i < NB; i += 256) hist[i] = 0;
    __syncthreads();
    const int chunk = (E + NBLK - 1) / NBLK;
    const int lo = blockIdx.x * chunk;
    const int hi = min(E, lo + chunk);
    for (int e = lo + (int)threadIdx.x; e < hi; e += 256)
        atomicAdd(&hist[src[e] >> LOCB], 1);
    __syncthreads();
    for (int i = threadIdx.x; i < NB; i += 256)
        M[blockIdx.x * NB + i] = hist[i];
}

__global__ __launch_bounds__(256) void colsum_kernel(
    const int* __restrict__ M, int* __restrict__ colsum)
{
    const int B = blockIdx.x * 256 + (int)threadIdx.x;
    int s = 0;
    for (int b = 0; b < NBLK; b++) s += M[b * NB + B];
    colsum[B] = s;
}

__global__ __launch_bounds__(1024) void scan_bucket(
    const int* __restrict__ colsum, int* __restrict__ bbase)
{
    __shared__ int part[NB];
    const int t = threadIdx.x;
    const int own = colsum[t];
    part[t] = own;
    __syncthreads();
    for (int d = 1; d < NB; d <<= 1) {
        int v = (t >= d) ? part[t - d] : 0;
        __syncthreads();
        part[t] += v;
        __syncthreads();
    }
    bbase[t] = part[t] - own;
    if (t == NB - 1) bbase[NB] = part[t];
}

__global__ __launch_bounds__(256) void rowbase_kernel(
    int* __restrict__ M, const int* __restrict__ bbase)
{
    const int B = blockIdx.x * 256 + (int)threadIdx.x;
    int run = bbase[B];
    for (int b = 0; b < NBLK; b++) {
        int c = M[b * NB + B];
        M[b * NB + B] = run;
        run += c;
    }
}

__global__ __launch_bounds__(256) void scatter_coarse(
    const int* __restrict__ src, const int* __restrict__ dst,
    const int* __restrict__ M, int* __restrict__ pk, int E)
{
    __shared__ int cur[NB];
    for (int i = threadIdx.x; i < NB; i += 256) cur[i] = M[blockIdx.x * NB + i];
    __syncthreads();
    const int chunk = (E + NBLK - 1) / NBLK;
    const int lo = blockIdx.x * chunk;
    const int hi = min(E, lo + chunk);
    for (int e = lo + (int)threadIdx.x; e < hi; e += 256) {
        const int s = src[e];
        const int p = atomicAdd(&cur[s >> LOCB], 1);
        pk[p] = ((s & 127) << 17) | dst[e];      // dst < 2^17
    }
}

// ---------------- per-bucket gather + LN + ELU (local CSR built in LDS) ----------------
__global__ __launch_bounds__(256) void gather_bucket(
    const __half* __restrict__ hh, const float* __restrict__ sl, const float* __restrict__ sr,
    const int* __restrict__ pk, const int* __restrict__ bbase,
    const float* __restrict__ gamma, const float* __restrict__ beta,
    float* __restrict__ out, int n)
{
    __shared__ int ldst[LDSE];
    __shared__ int lhist[128];
    __shared__ int sc[256];
    __shared__ int loff[128];
    __shared__ int lend[128];
    __shared__ int cur[128];

    const int B  = blockIdx.x;
    const int b0 = bbase[B], b1 = bbase[B + 1];
    const int cnt = b1 - b0;
    const int t  = threadIdx.x;
    const int lane = t & 63;
    const int wv   = t >> 6;

    // phase 1: local histogram over src&127
    if (t < 128) lhist[t] = 0;
    __syncthreads();
    for (int j = t; j < cnt; j += 256)
        atomicAdd(&lhist[pk[b0 + j] >> 17], 1);
    __syncthreads();

    // phase 2: 128-entry scan
    const int v = (t < 128) ? lhist[t] : 0;
    sc[t] = v;
    __syncthreads();
    for (int d = 1; d < 256; d <<= 1) {
        int u = (t >= d) ? sc[t - d] : 0;
        __syncthreads();
        sc[t] += u;
        __syncthreads();
    }
    if (t < 128) {
        loff[t] = sc[t] - v;
        lend[t] = sc[t];
        cur[t]  = sc[t] - v;
    }
    __syncthreads();

    // phase 3: place dst into local sorted order (pk slice is L2-hot)
    for (int j = t; j < cnt; j += 256) {
        const int w = pk[b0 + j];
        const int p = atomicAdd(&cur[w >> 17], 1);
        if (p < LDSE) ldst[p] = w & 0x1FFFF;
    }
    __syncthreads();

    // phase 4: 4 waves x 32 nodes
    const float gm = gamma[lane], bt = beta[lane];
    for (int li = wv * 32; li < wv * 32 + 32; li++) {
        const int i = (B << LOCB) + li;
        if (i >= n) break;
        const int e0 = loff[li], e1 = lend[li];
        const float sli = sl[i];
        float acc = 0.f;

        for (int base = e0; base < e1; base += 64) {
            const int j = base + lane;
            int d = 0; float w = 0.f;
            if (j < e1) {
                d = ldst[j];
                const float scv = sli + sr[d];
                const float lr = scv > 0.f ? scv : ALPHA * scv;
                w = __expf(-lr);
            }
            const int m = min(64, e1 - base);
            int tt = 0;
            for (; tt + 3 < m; tt += 4) {
                int   d0 = __shfl(d, tt),   d1 = __shfl(d, tt+1),
                      d2 = __shfl(d, tt+2), d3 = __shfl(d, tt+3);
                float w0 = __shfl(w, tt),   w1 = __shfl(w, tt+1),
                      w2 = __shfl(w, tt+2), w3 = __shfl(w, tt+3);
                float h0 = __half2float(hh[(size_t)d0 * OUTF + lane]);
                float h1 = __half2float(hh[(size_t)d1 * OUTF + lane]);
                float h2 = __half2float(hh[(size_t)d2 * OUTF + lane]);
                float h3 = __half2float(hh[(size_t)d3 * OUTF + lane]);
                acc = fmaf(w0, h0, acc); acc = fmaf(w1, h1, acc);
                acc = fmaf(w2, h2, acc); acc = fmaf(w3, h3, acc);
            }
            for (; tt < m; tt++) {
                int   dt = __shfl(d, tt);
                float wt = __shfl(w, tt);
                acc = fmaf(wt, __half2float(hh[(size_t)dt * OUTF + lane]), acc);
            }
        }

        float mu = acc;
        for (int s = 32; s; s >>= 1) mu += __shfl_xor(mu, s);
        mu *= (1.f / 64.f);
        const float dv = acc - mu;
        float vv = dv * dv;
        for (int s = 32; s; s >>= 1) vv += __shfl_xor(vv, s);
        vv *= (1.f / 64.f);
        const float y = dv * rsqrtf(vv + LN_EPS) * gm + bt;
        out[(size_t)i * OUTF + lane] = y > 0.f ? y : expm1f(y);
    }
}

// ---------------- launch ----------------
extern "C" void kernel_launch(void* const* d_in, const int* in_sizes, int n_in,
                              void* d_out, int out_size, void* d_ws, size_t ws_size,
                              hipStream_t stream)
{
    const float* x     = (const float*)d_in[0];
    const int*   edge  = (const int*)  d_in[1];
    const float* W     = (const float*)d_in[2];
    const float* b     = (const float*)d_in[3];
    const float* a     = (const float*)d_in[4];
    const float* gamma = (const float*)d_in[5];
    const float* beta  = (const float*)d_in[6];
    float* out = (float*)d_out;

    const int n = in_sizes[0] / INF_;   // 100000
    const int E = in_sizes[1] / 2;      // 3200000
    const int* src = edge;
    const int* dst = edge + E;
    const int nbuck = (n + 127) >> 7;   // 782 buckets

    char* ws = (char*)d_ws;
    size_t offb = 0;
    auto alloc = [&](size_t bytes) -> void* {
        void* p = ws + offb;
        offb = (offb + bytes + 255) & ~(size_t)255;
        return p;
    };
    __half* hh    = (__half*)alloc((size_t)n * OUTF * 2);
    float*  sl    = (float*) alloc((size_t)n * 4);
    float*  sr    = (float*) alloc((size_t)n * 4);
    int*    M     = (int*)   alloc((size_t)NBLK * NB * 4);   // 2 MB
    int*    colsum= (int*)   alloc((size_t)NB * 4);
    int*    bbase = (int*)   alloc((size_t)(NB + 1) * 4);
    int*    pk    = (int*)   alloc((size_t)E * 4);

    hipMemsetAsync(M, 0, (size_t)NBLK * NB * 4, stream);

    hipLaunchKernelGGL(count_coarse,   dim3(NBLK),   dim3(256),  0, stream, src, M, E);
    hipLaunchKernelGGL(colsum_kernel,  dim3(NB/256), dim3(256),  0, stream, M, colsum);
    hipLaunchKernelGGL(scan_bucket,    dim3(1),      dim3(1024), 0, stream, colsum, bbase);
    hipLaunchKernelGGL(rowbase_kernel, dim3(NB/256), dim3(256),  0, stream, M, bbase);
    hipLaunchKernelGGL(scatter_coarse, dim3(NBLK),   dim3(256),  0, stream, src, dst, M, pk, E);
    hipLaunchKernelGGL(gemm_kernel,    dim3(1024),   dim3(256),  0, stream, x, W, b, a, hh, sl, sr, n);
    hipLaunchKernelGGL(gather_bucket,  dim3(nbuck),  dim3(256),  0, stream, hh, sl, sr, pk, bbase, gamma, beta, out, n);
}

// Round 6
// 372.124 us; speedup vs baseline: 1.1343x; 1.1343x over previous
//
#include <hip/hip_runtime.h>
#include <hip/hip_fp16.h>
#include <cstdint>
#include <cstddef>

#define INF_  128
#define OUTF  64
#define ALPHA 0.2f
#define LN_EPS 1e-5f

#define NB    1024        // coarse buckets (src >> 7)
#define LOCB  7           // 128 local nodes per bucket
#define NBLK  512         // edge-partition blocks for count/scatter passes

// ---------------- GEMM: h(fp16) = x @ W^T + b, sl = h@a_l, sr = h@a_r ----------------
__global__ __launch_bounds__(256) void gemm_kernel(
    const float* __restrict__ x, const float* __restrict__ W,
    const float* __restrict__ b, const float* __restrict__ a,
    __half* __restrict__ hh, float* __restrict__ sl, float* __restrict__ sr, int n)
{
    __shared__ float4 Wq[32][64];          // Wq[kq][o]: lane-stride 16B, conflict-free
    __shared__ float4 xs[4][8][32];

    const int tid  = threadIdx.x;
    const int lane = tid & 63;
    const int wv   = tid >> 6;

    for (int idx = tid; idx < 2048; idx += 256) {
        int kq = idx >> 6, o = idx & 63;
        Wq[kq][o] = ((const float4*)W)[o * 32 + kq];
    }
    __syncthreads();

    const float bb = b[lane];
    const float al = a[lane];
    const float ar = a[OUTF + lane];

    const int ngroups = (n + 31) >> 5;
    for (int g = blockIdx.x; g < ngroups; g += gridDim.x) {
        const int node0 = g * 32 + wv * 8;
        for (int t = lane; t < 8 * 32; t += 64) {
            int r = t >> 5, q = t & 31;
            int nd = node0 + r; if (nd >= n) nd = 0;
            xs[wv][r][q] = ((const float4*)x)[(size_t)nd * 32 + q];
        }
        __syncthreads();

        float acc[8];
        #pragma unroll
        for (int r = 0; r < 8; r++) acc[r] = bb;

        #pragma unroll 4
        for (int kq = 0; kq < 32; kq++) {
            const float4 wq = Wq[kq][lane];
            #pragma unroll
            for (int r = 0; r < 8; r++) {
                const float4 xq = xs[wv][r][kq];   // wave-uniform broadcast read
                acc[r] = fmaf(wq.x, xq.x, acc[r]);
                acc[r] = fmaf(wq.y, xq.y, acc[r]);
                acc[r] = fmaf(wq.z, xq.z, acc[r]);
                acc[r] = fmaf(wq.w, xq.w, acc[r]);
            }
        }

        #pragma unroll
        for (int r = 0; r < 8; r++) {
            const int node = node0 + r;
            const float v = acc[r];
            float p = v * al, q = v * ar;
            for (int s = 32; s; s >>= 1) {
                p += __shfl_down(p, s);
                q += __shfl_down(q, s);
            }
            if (node < n) {
                hh[(size_t)node * OUTF + lane] = __float2half(v);
                if (lane == 0) { sl[node] = p; sr[node] = q; }
            }
        }
        __syncthreads();
    }
}

// ---------------- coarse radix by src>>7 (LDS atomics only) ----------------
__global__ __launch_bounds__(256) void count_coarse(
    const int* __restrict__ src, int* __restrict__ M, int E)
{
    __shared__ int hist[NB];
    for (int i = threadIdx.x; i < NB; i += 256) hist[i] = 0;
    __syncthreads();
    const int chunk = (E + NBLK - 1) / NBLK;
    const int lo = blockIdx.x * chunk;
    const int hi = min(E, lo + chunk);
    for (int e = lo + (int)threadIdx.x; e < hi; e += 256)
        atomicAdd(&hist[src[e] >> LOCB], 1);
    __syncthreads();
    for (int i = threadIdx.x; i < NB; i += 256)
        M[blockIdx.x * NB + i] = hist[i];
}

__global__ __launch_bounds__(256) void colsum_kernel(
    const int* __restrict__ M, int* __restrict__ colsum)
{
    const int B = blockIdx.x * 256 + (int)threadIdx.x;
    int s = 0;
    for (int b = 0; b < NBLK; b++) s += M[b * NB + B];
    colsum[B] = s;
}

__global__ __launch_bounds__(1024) void scan_bucket(
    const int* __restrict__ colsum, int* __restrict__ bbase)
{
    __shared__ int part[NB];
    const int t = threadIdx.x;
    const int own = colsum[t];
    part[t] = own;
    __syncthreads();
    for (int d = 1; d < NB; d <<= 1) {
        int v = (t >= d) ? part[t - d] : 0;
        __syncthreads();
        part[t] += v;
        __syncthreads();
    }
    bbase[t] = part[t] - own;
    if (t == NB - 1) bbase[NB] = part[t];
}

__global__ __launch_bounds__(256) void rowbase_kernel(
    int* __restrict__ M, const int* __restrict__ bbase)
{
    const int B = blockIdx.x * 256 + (int)threadIdx.x;
    int run = bbase[B];
    for (int b = 0; b < NBLK; b++) {
        int c = M[b * NB + B];
        M[b * NB + B] = run;
        run += c;
    }
}

__global__ __launch_bounds__(256) void scatter_coarse(
    const int* __restrict__ src, const int* __restrict__ dst,
    const int* __restrict__ M, int* __restrict__ pk, int E)
{
    __shared__ int cur[NB];
    for (int i = threadIdx.x; i < NB; i += 256) cur[i] = M[blockIdx.x * NB + i];
    __syncthreads();
    const int chunk = (E + NBLK - 1) / NBLK;
    const int lo = blockIdx.x * chunk;
    const int hi = min(E, lo + chunk);
    for (int e = lo + (int)threadIdx.x; e < hi; e += 256) {
        const int s = src[e];
        const int p = atomicAdd(&cur[s >> LOCB], 1);
        pk[p] = ((s & 127) << 17) | dst[e];      // dst < 2^17
    }
}

// ---------------- finalize: one block per bucket -> exact per-node CSR ----------------
__global__ __launch_bounds__(256) void finalize_kernel(
    const int* __restrict__ pk, const int* __restrict__ bbase,
    int* __restrict__ off, int* __restrict__ bdst, int n, int E)
{
    __shared__ int lhist[128];
    __shared__ int sc[256];
    __shared__ int cur2[128];

    const int B  = blockIdx.x;
    const int b0 = bbase[B], b1 = bbase[B + 1];
    const int t  = threadIdx.x;

    if (t < 128) lhist[t] = 0;
    __syncthreads();
    for (int j = b0 + t; j < b1; j += 256)
        atomicAdd(&lhist[pk[j] >> 17], 1);
    __syncthreads();

    const int v = (t < 128) ? lhist[t] : 0;
    sc[t] = v;
    __syncthreads();
    for (int d = 1; d < 256; d <<= 1) {
        int u = (t >= d) ? sc[t - d] : 0;
        __syncthreads();
        sc[t] += u;
        __syncthreads();
    }
    if (t < 128) {
        const int base = b0 + sc[t] - v;
        const int s = (B << LOCB) + t;
        if (s < n) off[s] = base;
        cur2[t] = base;
    }
    if (B == 0 && t == 0) off[n] = E;
    __syncthreads();

    for (int j = b0 + t; j < b1; j += 256) {
        const int w = pk[j];
        const int p = atomicAdd(&cur2[w >> 17], 1);
        bdst[p] = w & 0x1FFFF;       // within-bucket contiguous store, L2-local
    }
}

// ---------------- flat gather + LN + ELU (one wave per node, fp16 h) ----------------
__global__ __launch_bounds__(256) void gather_kernel(
    const __half* __restrict__ hh, const float* __restrict__ sl, const float* __restrict__ sr,
    const int* __restrict__ off, const int* __restrict__ bdst,
    const float* __restrict__ gamma, const float* __restrict__ beta,
    float* __restrict__ out, int n)
{
    const int lane = threadIdx.x & 63;
    const int wave = (int)((blockIdx.x * blockDim.x + threadIdx.x) >> 6);
    const int nw   = (int)((gridDim.x * blockDim.x) >> 6);
    const float gm = gamma[lane], bt = beta[lane];

    for (int i = wave; i < n; i += nw) {
        const int o0 = off[i], o1 = off[i + 1];
        const float sli = sl[i];
        float acc = 0.f;

        for (int base = o0; base < o1; base += 64) {
            const int j = base + lane;
            int d = 0; float w = 0.f;
            if (j < o1) {
                d = bdst[j];
                const float scv = sli + sr[d];
                const float lr = scv > 0.f ? scv : ALPHA * scv;
                w = __expf(-lr);
            }
            const int m = min(64, o1 - base);
            int t = 0;
            for (; t + 3 < m; t += 4) {          // 4 independent 128B row-gathers in flight
                int   d0 = __shfl(d, t),   d1 = __shfl(d, t+1),
                      d2 = __shfl(d, t+2), d3 = __shfl(d, t+3);
                float w0 = __shfl(w, t),   w1 = __shfl(w, t+1),
                      w2 = __shfl(w, t+2), w3 = __shfl(w, t+3);
                float h0 = __half2float(hh[(size_t)d0 * OUTF + lane]);
                float h1 = __half2float(hh[(size_t)d1 * OUTF + lane]);
                float h2 = __half2float(hh[(size_t)d2 * OUTF + lane]);
                float h3 = __half2float(hh[(size_t)d3 * OUTF + lane]);
                acc = fmaf(w0, h0, acc); acc = fmaf(w1, h1, acc);
                acc = fmaf(w2, h2, acc); acc = fmaf(w3, h3, acc);
            }
            for (; t < m; t++) {
                int   dt = __shfl(d, t);
                float wt = __shfl(w, t);
                acc = fmaf(wt, __half2float(hh[(size_t)dt * OUTF + lane]), acc);
            }
        }

        float mu = acc;
        for (int s = 32; s; s >>= 1) mu += __shfl_xor(mu, s);
        mu *= (1.f / 64.f);
        const float dv = acc - mu;
        float vv = dv * dv;
        for (int s = 32; s; s >>= 1) vv += __shfl_xor(vv, s);
        vv *= (1.f / 64.f);
        const float y = dv * rsqrtf(vv + LN_EPS) * gm + bt;
        out[(size_t)i * OUTF + lane] = y > 0.f ? y : expm1f(y);
    }
}

// ---------------- launch ----------------
extern "C" void kernel_launch(void* const* d_in, const int* in_sizes, int n_in,
                              void* d_out, int out_size, void* d_ws, size_t ws_size,
                              hipStream_t stream)
{
    const float* x     = (const float*)d_in[0];
    const int*   edge  = (const int*)  d_in[1];
    const float* W     = (const float*)d_in[2];
    const float* b     = (const float*)d_in[3];
    const float* a     = (const float*)d_in[4];
    const float* gamma = (const float*)d_in[5];
    const float* beta  = (const float*)d_in[6];
    float* out = (float*)d_out;

    const int n = in_sizes[0] / INF_;   // 100000
    const int E = in_sizes[1] / 2;      // 3200000
    const int* src = edge;
    const int* dst = edge + E;
    const int nbuck = (n + 127) >> 7;   // 782 buckets

    char* ws = (char*)d_ws;
    size_t offb = 0;
    auto alloc = [&](size_t bytes) -> void* {
        void* p = ws + offb;
        offb = (offb + bytes + 255) & ~(size_t)255;
        return p;
    };
    __half* hh    = (__half*)alloc((size_t)n * OUTF * 2);
    float*  sl    = (float*) alloc((size_t)n * 4);
    float*  sr    = (float*) alloc((size_t)n * 4);
    int*    M     = (int*)   alloc((size_t)NBLK * NB * 4);   // 2 MB
    int*    colsum= (int*)   alloc((size_t)NB * 4);
    int*    bbase = (int*)   alloc((size_t)(NB + 1) * 4);
    int*    off   = (int*)   alloc((size_t)(n + 1) * 4);
    int*    pk    = (int*)   alloc((size_t)E * 4);
    int*    bdst  = (int*)   alloc((size_t)E * 4);

    hipMemsetAsync(M, 0, (size_t)NBLK * NB * 4, stream);

    hipLaunchKernelGGL(count_coarse,    dim3(NBLK),   dim3(256),  0, stream, src, M, E);
    hipLaunchKernelGGL(colsum_kernel,   dim3(NB/256), dim3(256),  0, stream, M, colsum);
    hipLaunchKernelGGL(scan_bucket,     dim3(1),      dim3(1024), 0, stream, colsum, bbase);
    hipLaunchKernelGGL(rowbase_kernel,  dim3(NB/256), dim3(256),  0, stream, M, bbase);
    hipLaunchKernelGGL(scatter_coarse,  dim3(NBLK),   dim3(256),  0, stream, src, dst, M, pk, E);
    hipLaunchKernelGGL(finalize_kernel, dim3(nbuck),  dim3(256),  0, stream, pk, bbase, off, bdst, n, E);
    hipLaunchKernelGGL(gemm_kernel,     dim3(1024),   dim3(256),  0, stream, x, W, b, a, hh, sl, sr, n);
    hipLaunchKernelGGL(gather_kernel,   dim3(4096),   dim3(256),  0, stream, hh, sl, sr, off, bdst, gamma, beta, out, n);
}